// Round 1
// baseline (6202.471 us; speedup 1.0000x reference)
//
#include <hip/hip_runtime.h>
#include <math.h>

#define DIM 512
#define D_IN 4096
#define N_OBJS 2048
#define N_RELS 32768
#define N_OBJ_CLS 151
#define N_REL_CLS 51
#define EPSV 1e-5f

// d_out layout (floats)
#define OFF_HOBJ  0
#define OFF_HEDGE (N_OBJS*DIM)                      // 1,048,576
#define OFF_OLOG  (OFF_HEDGE + N_RELS*DIM)          // 17,825,792
#define OFF_PLOG  (OFF_OLOG + N_OBJS*N_OBJ_CLS)     // 18,135,040
#define OFF_LBL   (OFF_PLOG + N_RELS*N_REL_CLS)     // 19,806,208
#define OFF_RI    (OFF_LBL + N_OBJS)                // 19,808,256

__device__ __forceinline__ float sigmoidf_(float x) { return 1.0f / (1.0f + expf(-x)); }
__device__ __forceinline__ float dot4_(const float4 a, const float4 b) {
    return a.x*b.x + a.y*b.y + a.z*b.z + a.w*b.w;
}

// ---------------------------------------------------------------------------
// Generic tiled fp32 GEMM: C[M,N] = act(A[M,K] @ B[N,K]^T + bias[N])
// BM in {64,128}, BN=64, BK=32, 256 threads. M % BM == 0, K % 32 == 0 required;
// N arbitrary (bounds-checked).
// ---------------------------------------------------------------------------
template<int BM, bool RELU>
__global__ __launch_bounds__(256) void gemm_bias(
    const float* __restrict__ A, const float* __restrict__ B,
    const float* __restrict__ bias, float* __restrict__ C,
    int M, int N, int K)
{
    constexpr int BN = 64, BK = 32;
    constexpr int TM = BM / 16;             // rows per thread: 8 (BM=128) or 4 (BM=64)
    __shared__ float As[BK][BM + 4];
    __shared__ float Bs[BK][BN + 4];

    const int tid = threadIdx.x;
    const int tx = tid & 15, ty = tid >> 4;
    const int m0 = blockIdx.x * BM, n0 = blockIdx.y * BN;

    float acc[TM][4];
#pragma unroll
    for (int r = 0; r < TM; r++)
#pragma unroll
        for (int c = 0; c < 4; c++) acc[r][c] = 0.0f;

    for (int k0 = 0; k0 < K; k0 += BK) {
        // stage A (transposed into LDS)
#pragma unroll
        for (int i = tid; i < BM * BK / 4; i += 256) {
            int row = i >> 3, kq = i & 7;
            const float4 a = *(const float4*)&A[(size_t)(m0 + row) * K + k0 + kq * 4];
            As[kq*4+0][row] = a.x; As[kq*4+1][row] = a.y;
            As[kq*4+2][row] = a.z; As[kq*4+3][row] = a.w;
        }
        // stage B (transposed into LDS), N-bounds checked
#pragma unroll
        for (int i = tid; i < BN * BK / 4; i += 256) {
            int row = i >> 3, kq = i & 7;
            float4 b = make_float4(0.f, 0.f, 0.f, 0.f);
            if (n0 + row < N) b = *(const float4*)&B[(size_t)(n0 + row) * K + k0 + kq * 4];
            Bs[kq*4+0][row] = b.x; Bs[kq*4+1][row] = b.y;
            Bs[kq*4+2][row] = b.z; Bs[kq*4+3][row] = b.w;
        }
        __syncthreads();
#pragma unroll
        for (int k = 0; k < BK; k++) {
            const float4 bv = *(const float4*)&Bs[k][tx * 4];
            const float bb[4] = {bv.x, bv.y, bv.z, bv.w};
#pragma unroll
            for (int rq = 0; rq < TM / 4; rq++) {
                const float4 av = *(const float4*)&As[k][ty * TM + rq * 4];
                const float aa[4] = {av.x, av.y, av.z, av.w};
#pragma unroll
                for (int r = 0; r < 4; r++)
#pragma unroll
                    for (int c = 0; c < 4; c++)
                        acc[rq*4+r][c] += aa[r] * bb[c];
            }
        }
        __syncthreads();
    }
    // epilogue
#pragma unroll
    for (int r = 0; r < TM; r++) {
        const size_t m = m0 + ty * TM + r;
#pragma unroll
        for (int c = 0; c < 4; c++) {
            int n = n0 + tx * 4 + c;
            if (n < N) {
                float v = acc[r][c] + bias[n];
                if (RELU) v = fmaxf(v, 0.0f);
                C[m * N + n] = v;
            }
        }
    }
}

// ---------------------------------------------------------------------------
// Fused GRU cell: Hout = GRU(X, H).  Computes the 6 matmul panels
// (X@Wih^T 3 slices, H@Whh^T 3 slices) in one pass + pointwise epilogue.
// BM=64, BN=64, BK=16, 256 threads, 4x4 outputs x 6 accumulators per thread.
// ---------------------------------------------------------------------------
__global__ __launch_bounds__(256) void gru_fused(
    const float* __restrict__ X, const float* __restrict__ H,
    const float* __restrict__ Wih, const float* __restrict__ Whh,
    const float* __restrict__ bih, const float* __restrict__ bhh,
    float* __restrict__ Hout, int M)
{
    constexpr int BK = 16;
    __shared__ float Xs[BK][68], Hs[BK][68];
    __shared__ float Ws[3][BK][68], Vs[3][BK][68];

    const int tid = threadIdx.x;
    const int tx = tid & 15, ty = tid >> 4;
    const int m0 = blockIdx.x * 64, n0 = blockIdx.y * 64;

    float ai[3][4][4], ah[3][4][4];
#pragma unroll
    for (int g = 0; g < 3; g++)
#pragma unroll
        for (int r = 0; r < 4; r++)
#pragma unroll
            for (int c = 0; c < 4; c++) { ai[g][r][c] = 0.f; ah[g][r][c] = 0.f; }

    const int lrow = tid >> 2, lkq = tid & 3;   // 64 rows x 4 float4-slots

    for (int k0 = 0; k0 < DIM; k0 += BK) {
        {
            const float4 xv = *(const float4*)&X[(size_t)(m0 + lrow) * DIM + k0 + lkq * 4];
            Xs[lkq*4+0][lrow] = xv.x; Xs[lkq*4+1][lrow] = xv.y;
            Xs[lkq*4+2][lrow] = xv.z; Xs[lkq*4+3][lrow] = xv.w;
            const float4 hv = *(const float4*)&H[(size_t)(m0 + lrow) * DIM + k0 + lkq * 4];
            Hs[lkq*4+0][lrow] = hv.x; Hs[lkq*4+1][lrow] = hv.y;
            Hs[lkq*4+2][lrow] = hv.z; Hs[lkq*4+3][lrow] = hv.w;
        }
#pragma unroll
        for (int g = 0; g < 3; g++) {
            const float4 wv = *(const float4*)&Wih[(size_t)(g * DIM + n0 + lrow) * DIM + k0 + lkq * 4];
            Ws[g][lkq*4+0][lrow] = wv.x; Ws[g][lkq*4+1][lrow] = wv.y;
            Ws[g][lkq*4+2][lrow] = wv.z; Ws[g][lkq*4+3][lrow] = wv.w;
            const float4 vv = *(const float4*)&Whh[(size_t)(g * DIM + n0 + lrow) * DIM + k0 + lkq * 4];
            Vs[g][lkq*4+0][lrow] = vv.x; Vs[g][lkq*4+1][lrow] = vv.y;
            Vs[g][lkq*4+2][lrow] = vv.z; Vs[g][lkq*4+3][lrow] = vv.w;
        }
        __syncthreads();
#pragma unroll
        for (int k = 0; k < BK; k++) {
            const float4 xv = *(const float4*)&Xs[k][ty * 4];
            const float4 hv = *(const float4*)&Hs[k][ty * 4];
            const float xa[4] = {xv.x, xv.y, xv.z, xv.w};
            const float ha[4] = {hv.x, hv.y, hv.z, hv.w};
#pragma unroll
            for (int g = 0; g < 3; g++) {
                const float4 wv = *(const float4*)&Ws[g][k][tx * 4];
                const float4 vv = *(const float4*)&Vs[g][k][tx * 4];
                const float wa[4] = {wv.x, wv.y, wv.z, wv.w};
                const float va[4] = {vv.x, vv.y, vv.z, vv.w};
#pragma unroll
                for (int r = 0; r < 4; r++)
#pragma unroll
                    for (int c = 0; c < 4; c++) {
                        ai[g][r][c] += xa[r] * wa[c];
                        ah[g][r][c] += ha[r] * va[c];
                    }
            }
        }
        __syncthreads();
    }
    // pointwise GRU epilogue
#pragma unroll
    for (int r = 0; r < 4; r++) {
        const size_t m = m0 + ty * 4 + r;
#pragma unroll
        for (int c = 0; c < 4; c++) {
            const int j = n0 + tx * 4 + c;
            const float ir = ai[0][r][c] + bih[j];
            const float iz = ai[1][r][c] + bih[DIM + j];
            const float in_ = ai[2][r][c] + bih[2 * DIM + j];
            const float hr = ah[0][r][c] + bhh[j];
            const float hz = ah[1][r][c] + bhh[DIM + j];
            const float hn = ah[2][r][c] + bhh[2 * DIM + j];
            const float rr = sigmoidf_(ir + hr);
            const float zz = sigmoidf_(iz + hz);
            const float nn = tanhf(in_ + rr * hn);
            const float hp = H[m * DIM + j];
            Hout[m * DIM + j] = (1.0f - zz) * nn + zz * hp;
        }
    }
}

// ---------------------------------------------------------------------------
// per-edge degree counts
// ---------------------------------------------------------------------------
__global__ __launch_bounds__(256) void count_kernel(const int* __restrict__ rel,
                                                    float* cnt_s, float* cnt_o)
{
    const int e = blockIdx.x * 256 + threadIdx.x;
    atomicAdd(&cnt_s[rel[2 * e]], 1.0f);
    atomicAdd(&cnt_o[rel[2 * e + 1]], 1.0f);
}

// ---------------------------------------------------------------------------
// 4 scalar gates per edge; one 64-lane wave per edge (4 edges per block)
// g layout: [sn | on | se | oe], each N_RELS
// ---------------------------------------------------------------------------
__global__ __launch_bounds__(256) void gates_kernel(
    const float* __restrict__ h_obj, const float* __restrict__ h_edge,
    const int* __restrict__ rel,
    const float* __restrict__ wsn, const float* __restrict__ bsn,
    const float* __restrict__ won, const float* __restrict__ bon,
    const float* __restrict__ wse, const float* __restrict__ bse,
    const float* __restrict__ woe, const float* __restrict__ boe,
    float* __restrict__ g)
{
    const int wid = threadIdx.x >> 6;
    const int lane = threadIdx.x & 63;
    const int e = blockIdx.x * 4 + wid;
    const int s = rel[2 * e], o = rel[2 * e + 1];

    const float4* hs4 = (const float4*)(h_obj + (size_t)s * DIM);
    const float4* ho4 = (const float4*)(h_obj + (size_t)o * DIM);
    const float4* he4 = (const float4*)(h_edge + (size_t)e * DIM);
    const float4* wsn4 = (const float4*)wsn;
    const float4* won4 = (const float4*)won;
    const float4* wse4 = (const float4*)wse;
    const float4* woe4 = (const float4*)woe;

    float p0 = 0.f, p1 = 0.f, p2 = 0.f, p3 = 0.f;
#pragma unroll
    for (int half = 0; half < 2; half++) {
        const int kq = half * 64 + lane;     // 128 float4 = 512 floats
        const float4 vs = hs4[kq], vo = ho4[kq], ve = he4[kq];
        p0 += dot4_(vs, wsn4[kq]) + dot4_(ve, wsn4[128 + kq]);
        p1 += dot4_(vo, won4[kq]) + dot4_(ve, won4[128 + kq]);
        p2 += dot4_(vs, wse4[kq]) + dot4_(ve, wse4[128 + kq]);
        p3 += dot4_(vo, woe4[kq]) + dot4_(ve, woe4[128 + kq]);
    }
#pragma unroll
    for (int off = 32; off; off >>= 1) {
        p0 += __shfl_xor(p0, off);
        p1 += __shfl_xor(p1, off);
        p2 += __shfl_xor(p2, off);
        p3 += __shfl_xor(p3, off);
    }
    if (lane == 0) {
        g[e] = sigmoidf_(p0 + bsn[0]);
        g[N_RELS + e] = sigmoidf_(p1 + bon[0]);
        g[2 * N_RELS + e] = sigmoidf_(p2 + bse[0]);
        g[3 * N_RELS + e] = sigmoidf_(p3 + boe[0]);
    }
}

// ---------------------------------------------------------------------------
// per-edge pass: scatter node messages (pre-scaled, single accumulator) and
// write edge messages. One block (256 threads) per edge.
// ---------------------------------------------------------------------------
__global__ __launch_bounds__(256) void edge_pass(
    const float* __restrict__ h_obj, const float* __restrict__ h_edge,
    const int* __restrict__ rel, const float* __restrict__ g,
    const float* __restrict__ cnt_s, const float* __restrict__ cnt_o,
    float* __restrict__ nm, float* __restrict__ em)
{
    const int e = blockIdx.x;
    const int s = rel[2 * e], o = rel[2 * e + 1];
    const float gsn = g[e], gon = g[N_RELS + e];
    const float gse = g[2 * N_RELS + e], goe = g[3 * N_RELS + e];
    const float as = 0.5f * gsn / (cnt_s[s] + EPSV);
    const float ao = 0.5f * gon / (cnt_o[o] + EPSV);
#pragma unroll
    for (int it = 0; it < 2; it++) {
        const int c = threadIdx.x + it * 256;
        const float he = h_edge[(size_t)e * DIM + c];
        const float hs = h_obj[(size_t)s * DIM + c];
        const float ho = h_obj[(size_t)o * DIM + c];
        atomicAdd(&nm[(size_t)s * DIM + c], as * he);
        atomicAdd(&nm[(size_t)o * DIM + c], ao * he);
        em[(size_t)e * DIM + c] = 0.5f * (gse * hs + goe * ho);
    }
}

// ---------------------------------------------------------------------------
// argmax over logits[:,1:] + 1, written as float. One wave per row.
// ---------------------------------------------------------------------------
__global__ __launch_bounds__(256) void argmax_kernel(const float* __restrict__ logits,
                                                     float* __restrict__ out)
{
    const int row = blockIdx.x * 4 + (threadIdx.x >> 6);
    const int lane = threadIdx.x & 63;
    float bv = -1e30f; int bi = 1;
    for (int j = 1 + lane; j < N_OBJ_CLS; j += 64) {
        const float v = logits[(size_t)row * N_OBJ_CLS + j];
        if (v > bv) { bv = v; bi = j; }
    }
#pragma unroll
    for (int off = 32; off; off >>= 1) {
        const float ov = __shfl_xor(bv, off);
        const int oi = __shfl_xor(bi, off);
        if (ov > bv || (ov == bv && oi < bi)) { bv = ov; bi = oi; }
    }
    if (lane == 0) out[row] = (float)bi;
}

__global__ __launch_bounds__(256) void relinds_kernel(const int* __restrict__ rel,
                                                      float* __restrict__ out)
{
    const int i = blockIdx.x * 256 + threadIdx.x;
    out[i] = (float)rel[i];
}

// ---------------------------------------------------------------------------
extern "C" void kernel_launch(void* const* d_in, const int* in_sizes, int n_in,
                              void* d_out, int out_size, void* d_ws, size_t ws_size,
                              hipStream_t stream)
{
    const float* x_obj = (const float*)d_in[0];
    const float* x_pred = (const float*)d_in[1];
    const int* rel = (const int*)d_in[2];
    const float* oe_w1 = (const float*)d_in[3];
    const float* oe_b1 = (const float*)d_in[4];
    const float* oe_w2 = (const float*)d_in[5];
    const float* oe_b2 = (const float*)d_in[6];
    const float* pe_w1 = (const float*)d_in[7];
    const float* pe_b1 = (const float*)d_in[8];
    const float* pe_w2 = (const float*)d_in[9];
    const float* pe_b2 = (const float*)d_in[10];
    const float* g_sn_w = (const float*)d_in[11];
    const float* g_sn_b = (const float*)d_in[12];
    const float* g_on_w = (const float*)d_in[13];
    const float* g_on_b = (const float*)d_in[14];
    const float* g_se_w = (const float*)d_in[15];
    const float* g_se_b = (const float*)d_in[16];
    const float* g_oe_w = (const float*)d_in[17];
    const float* g_oe_b = (const float*)d_in[18];
    const float* ngru_wih = (const float*)d_in[19];
    const float* ngru_whh = (const float*)d_in[20];
    const float* ngru_bih = (const float*)d_in[21];
    const float* ngru_bhh = (const float*)d_in[22];
    const float* egru_wih = (const float*)d_in[23];
    const float* egru_whh = (const float*)d_in[24];
    const float* egru_bih = (const float*)d_in[25];
    const float* egru_bhh = (const float*)d_in[26];
    const float* op_w = (const float*)d_in[27];
    const float* op_b = (const float*)d_in[28];
    const float* pp_w = (const float*)d_in[29];
    const float* pp_b = (const float*)d_in[30];

    float* out = (float*)d_out;
    float* ws = (float*)d_ws;

    // workspace layout (floats) — ~214 MB total
    float* tmp_e = ws;                                    // 32768*512 (enc hidden, reused as em)
    float* h_edgeA = tmp_e + (size_t)N_RELS * DIM;
    float* h_edgeB = h_edgeA + (size_t)N_RELS * DIM;
    float* tmp_o = h_edgeB + (size_t)N_RELS * DIM;        // 2048*512 (enc hidden, reused as nm)
    float* h_objA = tmp_o + (size_t)N_OBJS * DIM;
    float* h_objB = h_objA + (size_t)N_OBJS * DIM;
    float* gates = h_objB + (size_t)N_OBJS * DIM;         // 4*N_RELS
    float* cnts = gates + 4 * (size_t)N_RELS;             // 2*N_OBJS
    float* cnt_s = cnts;
    float* cnt_o = cnts + N_OBJS;
    float* em = tmp_e;
    float* nm = tmp_o;

    // degree counts
    hipMemsetAsync(cnts, 0, 2 * N_OBJS * sizeof(float), stream);
    count_kernel<<<N_RELS / 256, 256, 0, stream>>>(rel, cnt_s, cnt_o);

    // encoders
    gemm_bias<64, true><<<dim3(N_OBJS / 64, DIM / 64), 256, 0, stream>>>(
        x_obj, oe_w1, oe_b1, tmp_o, N_OBJS, DIM, D_IN);
    gemm_bias<64, false><<<dim3(N_OBJS / 64, DIM / 64), 256, 0, stream>>>(
        tmp_o, oe_w2, oe_b2, h_objA, N_OBJS, DIM, DIM);
    gemm_bias<128, true><<<dim3(N_RELS / 128, DIM / 64), 256, 0, stream>>>(
        x_pred, pe_w1, pe_b1, tmp_e, N_RELS, DIM, D_IN);
    gemm_bias<128, false><<<dim3(N_RELS / 128, DIM / 64), 256, 0, stream>>>(
        tmp_e, pe_w2, pe_b2, h_edgeA, N_RELS, DIM, DIM);

    // message-passing steps
    const float* co = h_objA;
    const float* ce = h_edgeA;
    for (int step = 0; step < 2; step++) {
        float* no = (step == 0) ? h_objB : (out + OFF_HOBJ);
        float* ne = (step == 0) ? h_edgeB : (out + OFF_HEDGE);

        gates_kernel<<<N_RELS / 4, 256, 0, stream>>>(
            co, ce, rel, g_sn_w, g_sn_b, g_on_w, g_on_b,
            g_se_w, g_se_b, g_oe_w, g_oe_b, gates);

        hipMemsetAsync(nm, 0, (size_t)N_OBJS * DIM * sizeof(float), stream);
        edge_pass<<<N_RELS, 256, 0, stream>>>(co, ce, rel, gates, cnt_s, cnt_o, nm, em);

        gru_fused<<<dim3(N_OBJS / 64, DIM / 64), 256, 0, stream>>>(
            nm, co, ngru_wih, ngru_whh, ngru_bih, ngru_bhh, no, N_OBJS);
        gru_fused<<<dim3(N_RELS / 64, DIM / 64), 256, 0, stream>>>(
            em, ce, egru_wih, egru_whh, egru_bih, egru_bhh, ne, N_RELS);

        co = no; ce = ne;
    }

    // classifiers
    gemm_bias<64, false><<<dim3(N_OBJS / 64, (N_OBJ_CLS + 63) / 64), 256, 0, stream>>>(
        co, op_w, op_b, out + OFF_OLOG, N_OBJS, N_OBJ_CLS, DIM);
    gemm_bias<128, false><<<dim3(N_RELS / 128, 1), 256, 0, stream>>>(
        ce, pp_w, pp_b, out + OFF_PLOG, N_RELS, N_REL_CLS, DIM);

    // argmax labels + rel_inds passthrough
    argmax_kernel<<<N_OBJS / 4, 256, 0, stream>>>(out + OFF_OLOG, out + OFF_LBL);
    relinds_kernel<<<(2 * N_RELS) / 256, 256, 0, stream>>>(rel, out + OFF_RI);
}

// Round 2
// 4330.685 us; speedup vs baseline: 1.4322x; 1.4322x over previous
//
#include <hip/hip_runtime.h>
#include <math.h>

typedef unsigned short u16;
typedef unsigned int u32;
typedef __bf16 bf16x8 __attribute__((ext_vector_type(8)));
typedef float f32x4 __attribute__((ext_vector_type(4)));

#define DIM 512
#define D_IN 4096
#define N_OBJS 2048
#define N_RELS 32768
#define N_OBJ_CLS 151
#define N_REL_CLS 51
#define EPSV 1e-5f

// d_out layout (floats)
#define OFF_HOBJ  0
#define OFF_HEDGE (N_OBJS*DIM)
#define OFF_OLOG  (OFF_HEDGE + N_RELS*DIM)
#define OFF_PLOG  (OFF_OLOG + N_OBJS*N_OBJ_CLS)
#define OFF_LBL   (OFF_PLOG + N_RELS*N_REL_CLS)
#define OFF_RI    (OFF_LBL + N_OBJS)

__device__ __forceinline__ float sigmoidf_(float x) { return 1.0f / (1.0f + expf(-x)); }
__device__ __forceinline__ float dot4_(const float4 a, const float4 b) {
    return a.x*b.x + a.y*b.y + a.z*b.z + a.w*b.w;
}
__device__ __forceinline__ u16 f2bf(float f) {          // fp32 -> bf16 RNE
    u32 u = __float_as_uint(f);
    return (u16)((u + 0x7FFFu + ((u >> 16) & 1u)) >> 16);
}
__device__ __forceinline__ float bf2f(u16 h) { return __uint_as_float(((u32)h) << 16); }

// convert 8 fp32 -> packed hi/lo bf16 (uint4 each)
__device__ __forceinline__ void cvt8(const float* f, uint4& h, uint4& l) {
    u32 hh[8], ll[8];
#pragma unroll
    for (int i = 0; i < 8; i++) {
        u16 x = f2bf(f[i]);
        hh[i] = x;
        ll[i] = f2bf(f[i] - bf2f(x));
    }
    h.x = hh[0] | (hh[1] << 16); h.y = hh[2] | (hh[3] << 16);
    h.z = hh[4] | (hh[5] << 16); h.w = hh[6] | (hh[7] << 16);
    l.x = ll[0] | (ll[1] << 16); l.y = ll[2] | (ll[3] << 16);
    l.z = ll[4] | (ll[5] << 16); l.w = ll[6] | (ll[7] << 16);
}

// LDS offset (u16 units) for (row, chunk8) in a [rows][32]-bf16 tile,
// XOR-swizzled: chunk' = chunk ^ ((row>>1)&3)  -> 2-way conflicts max (free)
__device__ __forceinline__ int swzo(int row, int c) {
    return row * 32 + ((c ^ ((row >> 1) & 3)) << 3);
}

// ---------------------------------------------------------------------------
// fp32 -> (hi,lo) bf16 split, flat array (n4 = n/4 float4 elements)
// ---------------------------------------------------------------------------
__global__ __launch_bounds__(256) void convert_split(const float* __restrict__ src,
    u16* __restrict__ hi, u16* __restrict__ lo, int n4)
{
    const int i = blockIdx.x * 256 + threadIdx.x;
    if (i >= n4) return;
    const float4 v = ((const float4*)src)[i];
    u16 h0 = f2bf(v.x), h1 = f2bf(v.y), h2 = f2bf(v.z), h3 = f2bf(v.w);
    u16 l0 = f2bf(v.x - bf2f(h0)), l1 = f2bf(v.y - bf2f(h1));
    u16 l2 = f2bf(v.z - bf2f(h2)), l3 = f2bf(v.w - bf2f(h3));
    ((ushort4*)hi)[i] = make_ushort4(h0, h1, h2, h3);
    ((ushort4*)lo)[i] = make_ushort4(l0, l1, l2, l3);
}

// ---------------------------------------------------------------------------
// Split-bf16 MFMA GEMM: C[M,N] = act(A_f32[M,K] @ Bsplit[N,K]^T + bias[N])
// 128x128 tile, 4 waves (wave tile 64x64), BK=32, 16x16x32 bf16 MFMA.
// M%128==0, K%32==0; N arbitrary (bounds-checked).
// ---------------------------------------------------------------------------
template<bool RELU>
__global__ __launch_bounds__(256, 2) void gemm_split(
    const float* __restrict__ A, const u16* __restrict__ Bhi, const u16* __restrict__ Blo,
    const float* __restrict__ bias, float* __restrict__ C, int M, int N, int K)
{
    __shared__ u16 sAh[128 * 32], sAl[128 * 32], sBh[128 * 32], sBl[128 * 32];
    const int t = threadIdx.x;
    const int m0 = blockIdx.y * 128, n0 = blockIdx.x * 128;
    const int wid = t >> 6, lane = t & 63;
    const int wm = (wid >> 1) * 64, wn = (wid & 1) * 64;
    const int lr = lane & 15, lk = lane >> 4;

    f32x4 acc[4][4] = {};

    const int sr = t >> 1;           // staging row 0..127
    const int sc = (t & 1) * 2;      // first 8-elem chunk: 0 or 2
    const float* Ap = A + (size_t)(m0 + sr) * K + (t & 1) * 16;
    const bool bvalid = (n0 + sr) < N;
    const u16* Bhp = Bhi + (size_t)(bvalid ? (n0 + sr) : 0) * K + (t & 1) * 16;
    const u16* Blp = Blo + (size_t)(bvalid ? (n0 + sr) : 0) * K + (t & 1) * 16;

    for (int k0 = 0; k0 < K; k0 += 32) {
        float fv[16];
        *(float4*)&fv[0]  = *(const float4*)(Ap + k0);
        *(float4*)&fv[4]  = *(const float4*)(Ap + k0 + 4);
        *(float4*)&fv[8]  = *(const float4*)(Ap + k0 + 8);
        *(float4*)&fv[12] = *(const float4*)(Ap + k0 + 12);
        uint4 bh0 = {0,0,0,0}, bh1 = {0,0,0,0}, bl0 = {0,0,0,0}, bl1 = {0,0,0,0};
        if (bvalid) {
            bh0 = *(const uint4*)(Bhp + k0); bh1 = *(const uint4*)(Bhp + k0 + 8);
            bl0 = *(const uint4*)(Blp + k0); bl1 = *(const uint4*)(Blp + k0 + 8);
        }
        uint4 ah0, ah1, al0, al1;
        cvt8(fv, ah0, al0); cvt8(fv + 8, ah1, al1);

        __syncthreads();   // previous iteration's LDS reads complete
        *(uint4*)&sAh[swzo(sr, sc)]     = ah0;
        *(uint4*)&sAh[swzo(sr, sc + 1)] = ah1;
        *(uint4*)&sAl[swzo(sr, sc)]     = al0;
        *(uint4*)&sAl[swzo(sr, sc + 1)] = al1;
        *(uint4*)&sBh[swzo(sr, sc)]     = bh0;
        *(uint4*)&sBh[swzo(sr, sc + 1)] = bh1;
        *(uint4*)&sBl[swzo(sr, sc)]     = bl0;
        *(uint4*)&sBl[swzo(sr, sc + 1)] = bl1;
        __syncthreads();

        bf16x8 ah[4], al[4], bh[4], bl[4];
#pragma unroll
        for (int f = 0; f < 4; f++) {
            const int row = wm + f * 16 + lr;
            const int off = swzo(row, lk);
            ah[f] = *(const bf16x8*)&sAh[off];
            al[f] = *(const bf16x8*)&sAl[off];
            const int col = wn + f * 16 + lr;
            const int offb = swzo(col, lk);
            bh[f] = *(const bf16x8*)&sBh[offb];
            bl[f] = *(const bf16x8*)&sBl[offb];
        }
#pragma unroll
        for (int fm = 0; fm < 4; fm++)
#pragma unroll
            for (int fn = 0; fn < 4; fn++) {
                acc[fm][fn] = __builtin_amdgcn_mfma_f32_16x16x32_bf16(ah[fm], bh[fn], acc[fm][fn], 0, 0, 0);
                acc[fm][fn] = __builtin_amdgcn_mfma_f32_16x16x32_bf16(al[fm], bh[fn], acc[fm][fn], 0, 0, 0);
                acc[fm][fn] = __builtin_amdgcn_mfma_f32_16x16x32_bf16(ah[fm], bl[fn], acc[fm][fn], 0, 0, 0);
            }
    }
    // epilogue: C/D layout col=lane&15, row=(lane>>4)*4+reg
#pragma unroll
    for (int fm = 0; fm < 4; fm++) {
        const int mrow = m0 + wm + fm * 16 + lk * 4;
#pragma unroll
        for (int fn = 0; fn < 4; fn++) {
            const int col = n0 + wn + fn * 16 + lr;
            if (col < N) {
                const float bv = bias[col];
#pragma unroll
                for (int j = 0; j < 4; j++) {
                    float v = acc[fm][fn][j] + bv;
                    if (RELU) v = fmaxf(v, 0.0f);
                    C[(size_t)(mrow + j) * N + col] = v;
                }
            }
        }
    }
}

// ---------------------------------------------------------------------------
// Fused split-bf16 GRU: Hout = GRU(X, H). 6 MFMA panels per (m,n) tile.
// Block tile 64(m) x 64(n), 4 waves (wave tile 32x32 per panel), BK=32.
// ---------------------------------------------------------------------------
__global__ __launch_bounds__(256) void gru_split(
    const float* __restrict__ X, const float* __restrict__ H,
    const u16* __restrict__ Wih_hi, const u16* __restrict__ Wih_lo,
    const u16* __restrict__ Whh_hi, const u16* __restrict__ Whh_lo,
    const float* __restrict__ bih, const float* __restrict__ bhh,
    float* __restrict__ Hout)
{
    __shared__ u16 sXh[64 * 32], sXl[64 * 32], sHh[64 * 32], sHl[64 * 32];
    __shared__ u16 sWh[6][64 * 32], sWl[6][64 * 32];
    const int t = threadIdx.x;
    const int m0 = blockIdx.y * 64, n0 = blockIdx.x * 64;
    const int wid = t >> 6, lane = t & 63;
    const int wm = (wid >> 1) * 32, wn = (wid & 1) * 32;
    const int lr = lane & 15, lk = lane >> 4;

    f32x4 aX[3][2][2] = {}, aH[3][2][2] = {};

    const int xr = t >> 2, xq = t & 3;     // X/H staging: 64 rows x 4 chunks
    const int wr = t & 63, wc = t >> 6;    // W staging: 64 rows x 4 chunks
    const float* Xp = X + (size_t)(m0 + xr) * DIM + xq * 8;
    const float* Hp = H + (size_t)(m0 + xr) * DIM + xq * 8;

    for (int k0 = 0; k0 < DIM; k0 += 32) {
        float fx[8], fh[8];
        *(float4*)&fx[0] = *(const float4*)(Xp + k0);
        *(float4*)&fx[4] = *(const float4*)(Xp + k0 + 4);
        *(float4*)&fh[0] = *(const float4*)(Hp + k0);
        *(float4*)&fh[4] = *(const float4*)(Hp + k0 + 4);
        uint4 wh[6], wl[6];
#pragma unroll
        for (int g = 0; g < 3; g++) {
            const size_t off = (size_t)(g * DIM + n0 + wr) * DIM + k0 + wc * 8;
            wh[g]     = *(const uint4*)(Wih_hi + off);
            wl[g]     = *(const uint4*)(Wih_lo + off);
            wh[3 + g] = *(const uint4*)(Whh_hi + off);
            wl[3 + g] = *(const uint4*)(Whh_lo + off);
        }
        uint4 xh, xl, hh, hl;
        cvt8(fx, xh, xl); cvt8(fh, hh, hl);

        __syncthreads();
        *(uint4*)&sXh[swzo(xr, xq)] = xh;
        *(uint4*)&sXl[swzo(xr, xq)] = xl;
        *(uint4*)&sHh[swzo(xr, xq)] = hh;
        *(uint4*)&sHl[swzo(xr, xq)] = hl;
#pragma unroll
        for (int g = 0; g < 6; g++) {
            *(uint4*)&sWh[g][swzo(wr, wc)] = wh[g];
            *(uint4*)&sWl[g][swzo(wr, wc)] = wl[g];
        }
        __syncthreads();

        bf16x8 xhf[2], xlf[2], hhf[2], hlf[2];
#pragma unroll
        for (int f = 0; f < 2; f++) {
            const int row = wm + f * 16 + lr;
            const int off = swzo(row, lk);
            xhf[f] = *(const bf16x8*)&sXh[off];
            xlf[f] = *(const bf16x8*)&sXl[off];
            hhf[f] = *(const bf16x8*)&sHh[off];
            hlf[f] = *(const bf16x8*)&sHl[off];
        }
#pragma unroll
        for (int p = 0; p < 3; p++) {
#pragma unroll
            for (int fn = 0; fn < 2; fn++) {
                const int col = wn + fn * 16 + lr;
                const int off = swzo(col, lk);
                const bf16x8 wh_ = *(const bf16x8*)&sWh[p][off];
                const bf16x8 wl_ = *(const bf16x8*)&sWl[p][off];
#pragma unroll
                for (int fm = 0; fm < 2; fm++) {
                    aX[p][fm][fn] = __builtin_amdgcn_mfma_f32_16x16x32_bf16(xhf[fm], wh_, aX[p][fm][fn], 0, 0, 0);
                    aX[p][fm][fn] = __builtin_amdgcn_mfma_f32_16x16x32_bf16(xlf[fm], wh_, aX[p][fm][fn], 0, 0, 0);
                    aX[p][fm][fn] = __builtin_amdgcn_mfma_f32_16x16x32_bf16(xhf[fm], wl_, aX[p][fm][fn], 0, 0, 0);
                }
                const bf16x8 vh_ = *(const bf16x8*)&sWh[3 + p][off];
                const bf16x8 vl_ = *(const bf16x8*)&sWl[3 + p][off];
#pragma unroll
                for (int fm = 0; fm < 2; fm++) {
                    aH[p][fm][fn] = __builtin_amdgcn_mfma_f32_16x16x32_bf16(hhf[fm], vh_, aH[p][fm][fn], 0, 0, 0);
                    aH[p][fm][fn] = __builtin_amdgcn_mfma_f32_16x16x32_bf16(hlf[fm], vh_, aH[p][fm][fn], 0, 0, 0);
                    aH[p][fm][fn] = __builtin_amdgcn_mfma_f32_16x16x32_bf16(hhf[fm], vl_, aH[p][fm][fn], 0, 0, 0);
                }
            }
        }
    }
    // pointwise GRU epilogue
#pragma unroll
    for (int fm = 0; fm < 2; fm++) {
        const int mrow = m0 + wm + fm * 16 + lk * 4;
#pragma unroll
        for (int fn = 0; fn < 2; fn++) {
            const int col = n0 + wn + fn * 16 + lr;
            const float b_ir = bih[col], b_iz = bih[DIM + col], b_in = bih[2 * DIM + col];
            const float b_hr = bhh[col], b_hz = bhh[DIM + col], b_hn = bhh[2 * DIM + col];
#pragma unroll
            for (int j = 0; j < 4; j++) {
                const float ir = aX[0][fm][fn][j] + b_ir;
                const float iz = aX[1][fm][fn][j] + b_iz;
                const float in_ = aX[2][fm][fn][j] + b_in;
                const float hr = aH[0][fm][fn][j] + b_hr;
                const float hz = aH[1][fm][fn][j] + b_hz;
                const float hn = aH[2][fm][fn][j] + b_hn;
                const float r = sigmoidf_(ir + hr);
                const float z = sigmoidf_(iz + hz);
                const float nn = tanhf(in_ + r * hn);
                const float hv = H[(size_t)(mrow + j) * DIM + col];
                Hout[(size_t)(mrow + j) * DIM + col] = (1.0f - z) * nn + z * hv;
            }
        }
    }
}

// ---------------------------------------------------------------------------
__global__ __launch_bounds__(256) void count_kernel(const int* __restrict__ rel,
                                                    float* cnt_s, float* cnt_o)
{
    const int e = blockIdx.x * 256 + threadIdx.x;
    atomicAdd(&cnt_s[rel[2 * e]], 1.0f);
    atomicAdd(&cnt_o[rel[2 * e + 1]], 1.0f);
}

__global__ __launch_bounds__(256) void gates_kernel(
    const float* __restrict__ h_obj, const float* __restrict__ h_edge,
    const int* __restrict__ rel,
    const float* __restrict__ wsn, const float* __restrict__ bsn,
    const float* __restrict__ won, const float* __restrict__ bon,
    const float* __restrict__ wse, const float* __restrict__ bse,
    const float* __restrict__ woe, const float* __restrict__ boe,
    float* __restrict__ g)
{
    const int wid = threadIdx.x >> 6;
    const int lane = threadIdx.x & 63;
    const int e = blockIdx.x * 4 + wid;
    const int s = rel[2 * e], o = rel[2 * e + 1];

    const float4* hs4 = (const float4*)(h_obj + (size_t)s * DIM);
    const float4* ho4 = (const float4*)(h_obj + (size_t)o * DIM);
    const float4* he4 = (const float4*)(h_edge + (size_t)e * DIM);
    const float4* wsn4 = (const float4*)wsn;
    const float4* won4 = (const float4*)won;
    const float4* wse4 = (const float4*)wse;
    const float4* woe4 = (const float4*)woe;

    float p0 = 0.f, p1 = 0.f, p2 = 0.f, p3 = 0.f;
#pragma unroll
    for (int half = 0; half < 2; half++) {
        const int kq = half * 64 + lane;
        const float4 vs = hs4[kq], vo = ho4[kq], ve = he4[kq];
        p0 += dot4_(vs, wsn4[kq]) + dot4_(ve, wsn4[128 + kq]);
        p1 += dot4_(vo, won4[kq]) + dot4_(ve, won4[128 + kq]);
        p2 += dot4_(vs, wse4[kq]) + dot4_(ve, wse4[128 + kq]);
        p3 += dot4_(vo, woe4[kq]) + dot4_(ve, woe4[128 + kq]);
    }
#pragma unroll
    for (int off = 32; off; off >>= 1) {
        p0 += __shfl_xor(p0, off);
        p1 += __shfl_xor(p1, off);
        p2 += __shfl_xor(p2, off);
        p3 += __shfl_xor(p3, off);
    }
    if (lane == 0) {
        g[e] = sigmoidf_(p0 + bsn[0]);
        g[N_RELS + e] = sigmoidf_(p1 + bon[0]);
        g[2 * N_RELS + e] = sigmoidf_(p2 + bse[0]);
        g[3 * N_RELS + e] = sigmoidf_(p3 + boe[0]);
    }
}

__global__ __launch_bounds__(256) void edge_pass(
    const float* __restrict__ h_obj, const float* __restrict__ h_edge,
    const int* __restrict__ rel, const float* __restrict__ g,
    const float* __restrict__ cnt_s, const float* __restrict__ cnt_o,
    float* __restrict__ nm, float* __restrict__ em)
{
    const int e = blockIdx.x;
    const int s = rel[2 * e], o = rel[2 * e + 1];
    const float gsn = g[e], gon = g[N_RELS + e];
    const float gse = g[2 * N_RELS + e], goe = g[3 * N_RELS + e];
    const float as = 0.5f * gsn / (cnt_s[s] + EPSV);
    const float ao = 0.5f * gon / (cnt_o[o] + EPSV);
#pragma unroll
    for (int it = 0; it < 2; it++) {
        const int c = threadIdx.x + it * 256;
        const float he = h_edge[(size_t)e * DIM + c];
        const float hs = h_obj[(size_t)s * DIM + c];
        const float ho = h_obj[(size_t)o * DIM + c];
        atomicAdd(&nm[(size_t)s * DIM + c], as * he);
        atomicAdd(&nm[(size_t)o * DIM + c], ao * he);
        em[(size_t)e * DIM + c] = 0.5f * (gse * hs + goe * ho);
    }
}

__global__ __launch_bounds__(256) void argmax_kernel(const float* __restrict__ logits,
                                                     float* __restrict__ out)
{
    const int row = blockIdx.x * 4 + (threadIdx.x >> 6);
    const int lane = threadIdx.x & 63;
    float bv = -1e30f; int bi = 1;
    for (int j = 1 + lane; j < N_OBJ_CLS; j += 64) {
        const float v = logits[(size_t)row * N_OBJ_CLS + j];
        if (v > bv) { bv = v; bi = j; }
    }
#pragma unroll
    for (int off = 32; off; off >>= 1) {
        const float ov = __shfl_xor(bv, off);
        const int oi = __shfl_xor(bi, off);
        if (ov > bv || (ov == bv && oi < bi)) { bv = ov; bi = oi; }
    }
    if (lane == 0) out[row] = (float)bi;
}

__global__ __launch_bounds__(256) void relinds_kernel(const int* __restrict__ rel,
                                                      float* __restrict__ out)
{
    const int i = blockIdx.x * 256 + threadIdx.x;
    out[i] = (float)rel[i];
}

// ---------------------------------------------------------------------------
extern "C" void kernel_launch(void* const* d_in, const int* in_sizes, int n_in,
                              void* d_out, int out_size, void* d_ws, size_t ws_size,
                              hipStream_t stream)
{
    const float* x_obj = (const float*)d_in[0];
    const float* x_pred = (const float*)d_in[1];
    const int* rel = (const int*)d_in[2];
    const float* oe_w1 = (const float*)d_in[3];
    const float* oe_b1 = (const float*)d_in[4];
    const float* oe_w2 = (const float*)d_in[5];
    const float* oe_b2 = (const float*)d_in[6];
    const float* pe_w1 = (const float*)d_in[7];
    const float* pe_b1 = (const float*)d_in[8];
    const float* pe_w2 = (const float*)d_in[9];
    const float* pe_b2 = (const float*)d_in[10];
    const float* g_sn_w = (const float*)d_in[11];
    const float* g_sn_b = (const float*)d_in[12];
    const float* g_on_w = (const float*)d_in[13];
    const float* g_on_b = (const float*)d_in[14];
    const float* g_se_w = (const float*)d_in[15];
    const float* g_se_b = (const float*)d_in[16];
    const float* g_oe_w = (const float*)d_in[17];
    const float* g_oe_b = (const float*)d_in[18];
    const float* ngru_wih = (const float*)d_in[19];
    const float* ngru_whh = (const float*)d_in[20];
    const float* ngru_bih = (const float*)d_in[21];
    const float* ngru_bhh = (const float*)d_in[22];
    const float* egru_wih = (const float*)d_in[23];
    const float* egru_whh = (const float*)d_in[24];
    const float* egru_bih = (const float*)d_in[25];
    const float* egru_bhh = (const float*)d_in[26];
    const float* op_w = (const float*)d_in[27];
    const float* op_b = (const float*)d_in[28];
    const float* pp_w = (const float*)d_in[29];
    const float* pp_b = (const float*)d_in[30];

    float* out = (float*)d_out;
    float* ws = (float*)d_ws;

    // workspace layout (~175 MB)
    float* tmp_e = ws;                                  // 32768*512 (enc hidden / em)
    float* h_edgeA = tmp_e + (size_t)N_RELS * DIM;
    float* tmp_o = h_edgeA + (size_t)N_RELS * DIM;      // 2048*512 (enc hidden / nm)
    float* h_objA = tmp_o + (size_t)N_OBJS * DIM;
    float* gates = h_objA + (size_t)N_OBJS * DIM;       // 4*N_RELS
    float* cnts = gates + 4 * (size_t)N_RELS;           // 2*N_OBJS
    float* cnt_s = cnts;
    float* cnt_o = cnts + N_OBJS;
    float* em = tmp_e;
    float* nm = tmp_o;

    // split-weight area (u16)
    u16* wp = (u16*)(cnts + 2 * N_OBJS);
    const int s_big = DIM * D_IN, s_sq = DIM * DIM, s_gru = 3 * DIM * DIM;
    const int s_op = N_OBJ_CLS * DIM, s_pp = N_REL_CLS * DIM;
    u16 *oe1h = wp; wp += s_big; u16 *oe1l = wp; wp += s_big;
    u16 *pe1h = wp; wp += s_big; u16 *pe1l = wp; wp += s_big;
    u16 *oe2h = wp; wp += s_sq;  u16 *oe2l = wp; wp += s_sq;
    u16 *pe2h = wp; wp += s_sq;  u16 *pe2l = wp; wp += s_sq;
    u16 *nih_h = wp; wp += s_gru; u16 *nih_l = wp; wp += s_gru;
    u16 *nhh_h = wp; wp += s_gru; u16 *nhh_l = wp; wp += s_gru;
    u16 *eih_h = wp; wp += s_gru; u16 *eih_l = wp; wp += s_gru;
    u16 *ehh_h = wp; wp += s_gru; u16 *ehh_l = wp; wp += s_gru;
    u16 *oph = wp; wp += s_op;   u16 *opl = wp; wp += s_op;
    u16 *pph = wp; wp += s_pp;   u16 *ppl = wp; wp += s_pp;

    auto cvt = [&](const float* s, u16* h, u16* l, int n) {
        convert_split<<<(n / 4 + 255) / 256, 256, 0, stream>>>(s, h, l, n / 4);
    };
    cvt(oe_w1, oe1h, oe1l, s_big);
    cvt(pe_w1, pe1h, pe1l, s_big);
    cvt(oe_w2, oe2h, oe2l, s_sq);
    cvt(pe_w2, pe2h, pe2l, s_sq);
    cvt(ngru_wih, nih_h, nih_l, s_gru);
    cvt(ngru_whh, nhh_h, nhh_l, s_gru);
    cvt(egru_wih, eih_h, eih_l, s_gru);
    cvt(egru_whh, ehh_h, ehh_l, s_gru);
    cvt(op_w, oph, opl, s_op);
    cvt(pp_w, pph, ppl, s_pp);

    // degree counts
    hipMemsetAsync(cnts, 0, 2 * N_OBJS * sizeof(float), stream);
    count_kernel<<<N_RELS / 256, 256, 0, stream>>>(rel, cnt_s, cnt_o);

    // encoders (grid.x = n-blocks so same-A blocks run adjacently -> L2/L3 reuse)
    gemm_split<true><<<dim3(DIM / 128, N_OBJS / 128), 256, 0, stream>>>(
        x_obj, oe1h, oe1l, oe_b1, tmp_o, N_OBJS, DIM, D_IN);
    gemm_split<false><<<dim3(DIM / 128, N_OBJS / 128), 256, 0, stream>>>(
        tmp_o, oe2h, oe2l, oe_b2, h_objA, N_OBJS, DIM, DIM);
    gemm_split<true><<<dim3(DIM / 128, N_RELS / 128), 256, 0, stream>>>(
        x_pred, pe1h, pe1l, pe_b1, tmp_e, N_RELS, DIM, D_IN);
    gemm_split<false><<<dim3(DIM / 128, N_RELS / 128), 256, 0, stream>>>(
        tmp_e, pe2h, pe2l, pe_b2, h_edgeA, N_RELS, DIM, DIM);

    // message-passing steps; ping-pong via d_out regions, final lands in *_A
    for (int step = 0; step < 2; step++) {
        const float* co = (step == 0) ? h_objA : (out + OFF_HOBJ);
        const float* ce = (step == 0) ? h_edgeA : (out + OFF_HEDGE);
        float* no = (step == 0) ? (out + OFF_HOBJ) : h_objA;
        float* ne = (step == 0) ? (out + OFF_HEDGE) : h_edgeA;

        gates_kernel<<<N_RELS / 4, 256, 0, stream>>>(
            co, ce, rel, g_sn_w, g_sn_b, g_on_w, g_on_b,
            g_se_w, g_se_b, g_oe_w, g_oe_b, gates);

        hipMemsetAsync(nm, 0, (size_t)N_OBJS * DIM * sizeof(float), stream);
        edge_pass<<<N_RELS, 256, 0, stream>>>(co, ce, rel, gates, cnt_s, cnt_o, nm, em);

        gru_split<<<dim3(DIM / 64, N_OBJS / 64), 256, 0, stream>>>(
            nm, co, nih_h, nih_l, nhh_h, nhh_l, ngru_bih, ngru_bhh, no);
        gru_split<<<dim3(DIM / 64, N_RELS / 64), 256, 0, stream>>>(
            em, ce, eih_h, eih_l, ehh_h, ehh_l, egru_bih, egru_bhh, ne);
    }

    // final h_obj/h_edge -> d_out
    hipMemcpyAsync(out + OFF_HOBJ, h_objA, (size_t)N_OBJS * DIM * sizeof(float),
                   hipMemcpyDeviceToDevice, stream);
    hipMemcpyAsync(out + OFF_HEDGE, h_edgeA, (size_t)N_RELS * DIM * sizeof(float),
                   hipMemcpyDeviceToDevice, stream);

    // classifiers
    gemm_split<false><<<dim3((N_OBJ_CLS + 127) / 128, N_OBJS / 128), 256, 0, stream>>>(
        h_objA, oph, opl, op_b, out + OFF_OLOG, N_OBJS, N_OBJ_CLS, DIM);
    gemm_split<false><<<dim3((N_REL_CLS + 127) / 128, N_RELS / 128), 256, 0, stream>>>(
        h_edgeA, pph, ppl, pp_b, out + OFF_PLOG, N_RELS, N_REL_CLS, DIM);

    // labels + rel_inds passthrough
    argmax_kernel<<<N_OBJS / 4, 256, 0, stream>>>(out + OFF_OLOG, out + OFF_LBL);
    relinds_kernel<<<(2 * N_RELS) / 256, 256, 0, stream>>>(rel, out + OFF_RI);
}

// Round 3
// 2474.571 us; speedup vs baseline: 2.5065x; 1.7501x over previous
//
#include <hip/hip_runtime.h>
#include <math.h>

typedef unsigned short u16;
typedef unsigned int u32;
typedef __bf16 bf16x8 __attribute__((ext_vector_type(8)));
typedef float f32x4 __attribute__((ext_vector_type(4)));

#define DIM 512
#define D_IN 4096
#define N_OBJS 2048
#define N_RELS 32768
#define N_OBJ_CLS 151
#define N_REL_CLS 51
#define EPSV 1e-5f

// d_out layout (floats)
#define OFF_HOBJ  0
#define OFF_HEDGE (N_OBJS*DIM)
#define OFF_OLOG  (OFF_HEDGE + N_RELS*DIM)
#define OFF_PLOG  (OFF_OLOG + N_OBJS*N_OBJ_CLS)
#define OFF_LBL   (OFF_PLOG + N_RELS*N_REL_CLS)
#define OFF_RI    (OFF_LBL + N_OBJS)

__device__ __forceinline__ float sigmoidf_(float x) { return 1.0f / (1.0f + expf(-x)); }
__device__ __forceinline__ float dot4_(const float4 a, const float4 b) {
    return a.x*b.x + a.y*b.y + a.z*b.z + a.w*b.w;
}
__device__ __forceinline__ u16 f2bf(float f) {          // fp32 -> bf16 RNE
    u32 u = __float_as_uint(f);
    return (u16)((u + 0x7FFFu + ((u >> 16) & 1u)) >> 16);
}
__device__ __forceinline__ float bf2f(u16 h) { return __uint_as_float(((u32)h) << 16); }

// convert 8 fp32 -> packed hi/lo bf16 (uint4 each)
__device__ __forceinline__ void cvt8(const float* f, uint4& h, uint4& l) {
    u32 hh[8], ll[8];
#pragma unroll
    for (int i = 0; i < 8; i++) {
        u16 x = f2bf(f[i]);
        hh[i] = x;
        ll[i] = f2bf(f[i] - bf2f(x));
    }
    h.x = hh[0] | (hh[1] << 16); h.y = hh[2] | (hh[3] << 16);
    h.z = hh[4] | (hh[5] << 16); h.w = hh[6] | (hh[7] << 16);
    l.x = ll[0] | (ll[1] << 16); l.y = ll[2] | (ll[3] << 16);
    l.z = ll[4] | (ll[5] << 16); l.w = ll[6] | (ll[7] << 16);
}

// LDS offset (u16 units) for (row, chunk8) in a [rows][32]-bf16 tile,
// XOR-swizzled: chunk' = chunk ^ ((row>>1)&3)  -> 2-way conflicts max (free)
__device__ __forceinline__ int swzo(int row, int c) {
    return row * 32 + ((c ^ ((row >> 1) & 3)) << 3);
}

// ---------------------------------------------------------------------------
// fp32 -> (hi,lo) bf16 split, flat array (n4 = n/4 float4 elements)
// ---------------------------------------------------------------------------
__global__ __launch_bounds__(256) void convert_split(const float* __restrict__ src,
    u16* __restrict__ hi, u16* __restrict__ lo, int n4)
{
    const int i = blockIdx.x * 256 + threadIdx.x;
    if (i >= n4) return;
    const float4 v = ((const float4*)src)[i];
    u16 h0 = f2bf(v.x), h1 = f2bf(v.y), h2 = f2bf(v.z), h3 = f2bf(v.w);
    u16 l0 = f2bf(v.x - bf2f(h0)), l1 = f2bf(v.y - bf2f(h1));
    u16 l2 = f2bf(v.z - bf2f(h2)), l3 = f2bf(v.w - bf2f(h3));
    ((ushort4*)hi)[i] = make_ushort4(h0, h1, h2, h3);
    ((ushort4*)lo)[i] = make_ushort4(l0, l1, l2, l3);
}

// ---------------------------------------------------------------------------
// Split-bf16 MFMA GEMM (fp32 A, on-the-fly split): C = act(A @ Bsplit^T + bias)
// 128x128 tile, 4 waves (wave tile 64x64), BK=32, 16x16x32 bf16 MFMA.
// ---------------------------------------------------------------------------
template<bool RELU>
__global__ __launch_bounds__(256, 2) void gemm_split(
    const float* __restrict__ A, const u16* __restrict__ Bhi, const u16* __restrict__ Blo,
    const float* __restrict__ bias, float* __restrict__ C, int M, int N, int K)
{
    __shared__ u16 sAh[128 * 32], sAl[128 * 32], sBh[128 * 32], sBl[128 * 32];
    const int t = threadIdx.x;
    const int m0 = blockIdx.y * 128, n0 = blockIdx.x * 128;
    const int wid = t >> 6, lane = t & 63;
    const int wm = (wid >> 1) * 64, wn = (wid & 1) * 64;
    const int lr = lane & 15, lk = lane >> 4;

    f32x4 acc[4][4] = {};

    const int sr = t >> 1;
    const int sc = (t & 1) * 2;
    const float* Ap = A + (size_t)(m0 + sr) * K + (t & 1) * 16;
    const bool bvalid = (n0 + sr) < N;
    const u16* Bhp = Bhi + (size_t)(bvalid ? (n0 + sr) : 0) * K + (t & 1) * 16;
    const u16* Blp = Blo + (size_t)(bvalid ? (n0 + sr) : 0) * K + (t & 1) * 16;

    for (int k0 = 0; k0 < K; k0 += 32) {
        float fv[16];
        *(float4*)&fv[0]  = *(const float4*)(Ap + k0);
        *(float4*)&fv[4]  = *(const float4*)(Ap + k0 + 4);
        *(float4*)&fv[8]  = *(const float4*)(Ap + k0 + 8);
        *(float4*)&fv[12] = *(const float4*)(Ap + k0 + 12);
        uint4 bh0 = {0,0,0,0}, bh1 = {0,0,0,0}, bl0 = {0,0,0,0}, bl1 = {0,0,0,0};
        if (bvalid) {
            bh0 = *(const uint4*)(Bhp + k0); bh1 = *(const uint4*)(Bhp + k0 + 8);
            bl0 = *(const uint4*)(Blp + k0); bl1 = *(const uint4*)(Blp + k0 + 8);
        }
        uint4 ah0, ah1, al0, al1;
        cvt8(fv, ah0, al0); cvt8(fv + 8, ah1, al1);

        __syncthreads();
        *(uint4*)&sAh[swzo(sr, sc)]     = ah0;
        *(uint4*)&sAh[swzo(sr, sc + 1)] = ah1;
        *(uint4*)&sAl[swzo(sr, sc)]     = al0;
        *(uint4*)&sAl[swzo(sr, sc + 1)] = al1;
        *(uint4*)&sBh[swzo(sr, sc)]     = bh0;
        *(uint4*)&sBh[swzo(sr, sc + 1)] = bh1;
        *(uint4*)&sBl[swzo(sr, sc)]     = bl0;
        *(uint4*)&sBl[swzo(sr, sc + 1)] = bl1;
        __syncthreads();

        bf16x8 ah[4], al[4], bh[4], bl[4];
#pragma unroll
        for (int f = 0; f < 4; f++) {
            const int row = wm + f * 16 + lr;
            const int off = swzo(row, lk);
            ah[f] = *(const bf16x8*)&sAh[off];
            al[f] = *(const bf16x8*)&sAl[off];
            const int col = wn + f * 16 + lr;
            const int offb = swzo(col, lk);
            bh[f] = *(const bf16x8*)&sBh[offb];
            bl[f] = *(const bf16x8*)&sBl[offb];
        }
#pragma unroll
        for (int fm = 0; fm < 4; fm++)
#pragma unroll
            for (int fn = 0; fn < 4; fn++) {
                acc[fm][fn] = __builtin_amdgcn_mfma_f32_16x16x32_bf16(ah[fm], bh[fn], acc[fm][fn], 0, 0, 0);
                acc[fm][fn] = __builtin_amdgcn_mfma_f32_16x16x32_bf16(al[fm], bh[fn], acc[fm][fn], 0, 0, 0);
                acc[fm][fn] = __builtin_amdgcn_mfma_f32_16x16x32_bf16(ah[fm], bl[fn], acc[fm][fn], 0, 0, 0);
            }
    }
#pragma unroll
    for (int fm = 0; fm < 4; fm++) {
        const int mrow = m0 + wm + fm * 16 + lk * 4;
#pragma unroll
        for (int fn = 0; fn < 4; fn++) {
            const int col = n0 + wn + fn * 16 + lr;
            if (col < N) {
                const float bv = bias[col];
#pragma unroll
                for (int j = 0; j < 4; j++) {
                    float v = acc[fm][fn][j] + bv;
                    if (RELU) v = fmaxf(v, 0.0f);
                    C[(size_t)(mrow + j) * N + col] = v;
                }
            }
        }
    }
}

// ---------------------------------------------------------------------------
// Split-bf16 MFMA GEMM, BOTH sides pre-split u16 (no cvt in loop), with
// T14-style prefetch: next K-step's global loads issued before the MFMA block.
// C[M,N] = A @ B^T + bias.  M%128==0, K%32==0, N bounds-checked.
// ---------------------------------------------------------------------------
__global__ __launch_bounds__(256) void gemm_presplit(
    const u16* __restrict__ Ahi, const u16* __restrict__ Alo,
    const u16* __restrict__ Bhi, const u16* __restrict__ Blo,
    const float* __restrict__ bias, float* __restrict__ C, int M, int N, int K)
{
    __shared__ u16 sAh[128 * 32], sAl[128 * 32], sBh[128 * 32], sBl[128 * 32];
    const int t = threadIdx.x;
    const int m0 = blockIdx.y * 128, n0 = blockIdx.x * 128;
    const int wid = t >> 6, lane = t & 63;
    const int wm = (wid >> 1) * 64, wn = (wid & 1) * 64;
    const int lr = lane & 15, lk = lane >> 4;

    f32x4 acc[4][4] = {};

    const int sr = t >> 1;
    const int sc = (t & 1) * 2;
    const u16* Ahp = Ahi + (size_t)(m0 + sr) * K + (t & 1) * 16;
    const u16* Alp = Alo + (size_t)(m0 + sr) * K + (t & 1) * 16;
    const bool bvalid = (n0 + sr) < N;
    const u16* Bhp = Bhi + (size_t)(bvalid ? (n0 + sr) : 0) * K + (t & 1) * 16;
    const u16* Blp = Blo + (size_t)(bvalid ? (n0 + sr) : 0) * K + (t & 1) * 16;

    uint4 ah0, ah1, al0, al1, bh0, bh1, bl0, bl1;
    // preload k=0
    ah0 = *(const uint4*)(Ahp); ah1 = *(const uint4*)(Ahp + 8);
    al0 = *(const uint4*)(Alp); al1 = *(const uint4*)(Alp + 8);
    if (bvalid) {
        bh0 = *(const uint4*)(Bhp); bh1 = *(const uint4*)(Bhp + 8);
        bl0 = *(const uint4*)(Blp); bl1 = *(const uint4*)(Blp + 8);
    } else {
        bh0 = bh1 = bl0 = bl1 = make_uint4(0, 0, 0, 0);
    }

    for (int k0 = 0; k0 < K; k0 += 32) {
        __syncthreads();   // previous iteration's LDS reads complete
        *(uint4*)&sAh[swzo(sr, sc)]     = ah0;
        *(uint4*)&sAh[swzo(sr, sc + 1)] = ah1;
        *(uint4*)&sAl[swzo(sr, sc)]     = al0;
        *(uint4*)&sAl[swzo(sr, sc + 1)] = al1;
        *(uint4*)&sBh[swzo(sr, sc)]     = bh0;
        *(uint4*)&sBh[swzo(sr, sc + 1)] = bh1;
        *(uint4*)&sBl[swzo(sr, sc)]     = bl0;
        *(uint4*)&sBl[swzo(sr, sc + 1)] = bl1;
        __syncthreads();

        // issue next K-step's loads now; latency hides under this step's MFMAs
        const int kn = k0 + 32;
        if (kn < K) {
            ah0 = *(const uint4*)(Ahp + kn); ah1 = *(const uint4*)(Ahp + kn + 8);
            al0 = *(const uint4*)(Alp + kn); al1 = *(const uint4*)(Alp + kn + 8);
            if (bvalid) {
                bh0 = *(const uint4*)(Bhp + kn); bh1 = *(const uint4*)(Bhp + kn + 8);
                bl0 = *(const uint4*)(Blp + kn); bl1 = *(const uint4*)(Blp + kn + 8);
            }
        }

        bf16x8 ah[4], al[4], bh[4], bl[4];
#pragma unroll
        for (int f = 0; f < 4; f++) {
            const int row = wm + f * 16 + lr;
            const int off = swzo(row, lk);
            ah[f] = *(const bf16x8*)&sAh[off];
            al[f] = *(const bf16x8*)&sAl[off];
            const int col = wn + f * 16 + lr;
            const int offb = swzo(col, lk);
            bh[f] = *(const bf16x8*)&sBh[offb];
            bl[f] = *(const bf16x8*)&sBl[offb];
        }
#pragma unroll
        for (int fm = 0; fm < 4; fm++)
#pragma unroll
            for (int fn = 0; fn < 4; fn++) {
                acc[fm][fn] = __builtin_amdgcn_mfma_f32_16x16x32_bf16(ah[fm], bh[fn], acc[fm][fn], 0, 0, 0);
                acc[fm][fn] = __builtin_amdgcn_mfma_f32_16x16x32_bf16(al[fm], bh[fn], acc[fm][fn], 0, 0, 0);
                acc[fm][fn] = __builtin_amdgcn_mfma_f32_16x16x32_bf16(ah[fm], bl[fn], acc[fm][fn], 0, 0, 0);
            }
    }
#pragma unroll
    for (int fm = 0; fm < 4; fm++) {
        const int mrow = m0 + wm + fm * 16 + lk * 4;
#pragma unroll
        for (int fn = 0; fn < 4; fn++) {
            const int col = n0 + wn + fn * 16 + lr;
            if (col < N) {
                const float bv = bias[col];
#pragma unroll
                for (int j = 0; j < 4; j++)
                    C[(size_t)(mrow + j) * N + col] = acc[fm][fn][j] + bv;
            }
        }
    }
}

// ---------------------------------------------------------------------------
// GRU pointwise combine: gi/gh are [R x 1536] (r,z,n panels), H/Hout [R x 512]
// ---------------------------------------------------------------------------
__global__ __launch_bounds__(256) void gru_combine(
    const float* __restrict__ gi, const float* __restrict__ gh,
    const float* __restrict__ H, float* __restrict__ Hout, int R)
{
    const int idx = blockIdx.x * 256 + threadIdx.x;      // over R*128 float4s
    if (idx >= R * 128) return;
    const int r = idx >> 7, c4 = (idx & 127) * 4;
    const size_t gb = (size_t)r * 1536 + c4;
    const float4 ir4 = *(const float4*)&gi[gb];
    const float4 iz4 = *(const float4*)&gi[gb + 512];
    const float4 in4 = *(const float4*)&gi[gb + 1024];
    const float4 hr4 = *(const float4*)&gh[gb];
    const float4 hz4 = *(const float4*)&gh[gb + 512];
    const float4 hn4 = *(const float4*)&gh[gb + 1024];
    const float4 h4  = *(const float4*)&H[(size_t)r * 512 + c4];
    float4 o;
    {
        const float rr = sigmoidf_(ir4.x + hr4.x), zz = sigmoidf_(iz4.x + hz4.x);
        o.x = (1.0f - zz) * tanhf(in4.x + rr * hn4.x) + zz * h4.x;
    }
    {
        const float rr = sigmoidf_(ir4.y + hr4.y), zz = sigmoidf_(iz4.y + hz4.y);
        o.y = (1.0f - zz) * tanhf(in4.y + rr * hn4.y) + zz * h4.y;
    }
    {
        const float rr = sigmoidf_(ir4.z + hr4.z), zz = sigmoidf_(iz4.z + hz4.z);
        o.z = (1.0f - zz) * tanhf(in4.z + rr * hn4.z) + zz * h4.z;
    }
    {
        const float rr = sigmoidf_(ir4.w + hr4.w), zz = sigmoidf_(iz4.w + hz4.w);
        o.w = (1.0f - zz) * tanhf(in4.w + rr * hn4.w) + zz * h4.w;
    }
    *(float4*)&Hout[(size_t)r * 512 + c4] = o;
}

// ---------------------------------------------------------------------------
__global__ __launch_bounds__(256) void count_kernel(const int* __restrict__ rel,
                                                    float* cnt_s, float* cnt_o)
{
    const int e = blockIdx.x * 256 + threadIdx.x;
    atomicAdd(&cnt_s[rel[2 * e]], 1.0f);
    atomicAdd(&cnt_o[rel[2 * e + 1]], 1.0f);
}

__global__ __launch_bounds__(256) void gates_kernel(
    const float* __restrict__ h_obj, const float* __restrict__ h_edge,
    const int* __restrict__ rel,
    const float* __restrict__ wsn, const float* __restrict__ bsn,
    const float* __restrict__ won, const float* __restrict__ bon,
    const float* __restrict__ wse, const float* __restrict__ bse,
    const float* __restrict__ woe, const float* __restrict__ boe,
    float* __restrict__ g)
{
    const int wid = threadIdx.x >> 6;
    const int lane = threadIdx.x & 63;
    const int e = blockIdx.x * 4 + wid;
    const int s = rel[2 * e], o = rel[2 * e + 1];

    const float4* hs4 = (const float4*)(h_obj + (size_t)s * DIM);
    const float4* ho4 = (const float4*)(h_obj + (size_t)o * DIM);
    const float4* he4 = (const float4*)(h_edge + (size_t)e * DIM);
    const float4* wsn4 = (const float4*)wsn;
    const float4* won4 = (const float4*)won;
    const float4* wse4 = (const float4*)wse;
    const float4* woe4 = (const float4*)woe;

    float p0 = 0.f, p1 = 0.f, p2 = 0.f, p3 = 0.f;
#pragma unroll
    for (int half = 0; half < 2; half++) {
        const int kq = half * 64 + lane;
        const float4 vs = hs4[kq], vo = ho4[kq], ve = he4[kq];
        p0 += dot4_(vs, wsn4[kq]) + dot4_(ve, wsn4[128 + kq]);
        p1 += dot4_(vo, won4[kq]) + dot4_(ve, won4[128 + kq]);
        p2 += dot4_(vs, wse4[kq]) + dot4_(ve, wse4[128 + kq]);
        p3 += dot4_(vo, woe4[kq]) + dot4_(ve, woe4[128 + kq]);
    }
#pragma unroll
    for (int off = 32; off; off >>= 1) {
        p0 += __shfl_xor(p0, off);
        p1 += __shfl_xor(p1, off);
        p2 += __shfl_xor(p2, off);
        p3 += __shfl_xor(p3, off);
    }
    if (lane == 0) {
        g[e] = sigmoidf_(p0 + bsn[0]);
        g[N_RELS + e] = sigmoidf_(p1 + bon[0]);
        g[2 * N_RELS + e] = sigmoidf_(p2 + bse[0]);
        g[3 * N_RELS + e] = sigmoidf_(p3 + boe[0]);
    }
}

__global__ __launch_bounds__(256) void edge_pass(
    const float* __restrict__ h_obj, const float* __restrict__ h_edge,
    const int* __restrict__ rel, const float* __restrict__ g,
    const float* __restrict__ cnt_s, const float* __restrict__ cnt_o,
    float* __restrict__ nm, float* __restrict__ em)
{
    const int e = blockIdx.x;
    const int s = rel[2 * e], o = rel[2 * e + 1];
    const float gsn = g[e], gon = g[N_RELS + e];
    const float gse = g[2 * N_RELS + e], goe = g[3 * N_RELS + e];
    const float as = 0.5f * gsn / (cnt_s[s] + EPSV);
    const float ao = 0.5f * gon / (cnt_o[o] + EPSV);
#pragma unroll
    for (int it = 0; it < 2; it++) {
        const int c = threadIdx.x + it * 256;
        const float he = h_edge[(size_t)e * DIM + c];
        const float hs = h_obj[(size_t)s * DIM + c];
        const float ho = h_obj[(size_t)o * DIM + c];
        atomicAdd(&nm[(size_t)s * DIM + c], as * he);
        atomicAdd(&nm[(size_t)o * DIM + c], ao * he);
        em[(size_t)e * DIM + c] = 0.5f * (gse * hs + goe * ho);
    }
}

__global__ __launch_bounds__(256) void argmax_kernel(const float* __restrict__ logits,
                                                     float* __restrict__ out)
{
    const int row = blockIdx.x * 4 + (threadIdx.x >> 6);
    const int lane = threadIdx.x & 63;
    float bv = -1e30f; int bi = 1;
    for (int j = 1 + lane; j < N_OBJ_CLS; j += 64) {
        const float v = logits[(size_t)row * N_OBJ_CLS + j];
        if (v > bv) { bv = v; bi = j; }
    }
#pragma unroll
    for (int off = 32; off; off >>= 1) {
        const float ov = __shfl_xor(bv, off);
        const int oi = __shfl_xor(bi, off);
        if (ov > bv || (ov == bv && oi < bi)) { bv = ov; bi = oi; }
    }
    if (lane == 0) out[row] = (float)bi;
}

__global__ __launch_bounds__(256) void relinds_kernel(const int* __restrict__ rel,
                                                      float* __restrict__ out)
{
    const int i = blockIdx.x * 256 + threadIdx.x;
    out[i] = (float)rel[i];
}

// ---------------------------------------------------------------------------
extern "C" void kernel_launch(void* const* d_in, const int* in_sizes, int n_in,
                              void* d_out, int out_size, void* d_ws, size_t ws_size,
                              hipStream_t stream)
{
    const float* x_obj = (const float*)d_in[0];
    const float* x_pred = (const float*)d_in[1];
    const int* rel = (const int*)d_in[2];
    const float* oe_w1 = (const float*)d_in[3];
    const float* oe_b1 = (const float*)d_in[4];
    const float* oe_w2 = (const float*)d_in[5];
    const float* oe_b2 = (const float*)d_in[6];
    const float* pe_w1 = (const float*)d_in[7];
    const float* pe_b1 = (const float*)d_in[8];
    const float* pe_w2 = (const float*)d_in[9];
    const float* pe_b2 = (const float*)d_in[10];
    const float* g_sn_w = (const float*)d_in[11];
    const float* g_sn_b = (const float*)d_in[12];
    const float* g_on_w = (const float*)d_in[13];
    const float* g_on_b = (const float*)d_in[14];
    const float* g_se_w = (const float*)d_in[15];
    const float* g_se_b = (const float*)d_in[16];
    const float* g_oe_w = (const float*)d_in[17];
    const float* g_oe_b = (const float*)d_in[18];
    const float* ngru_wih = (const float*)d_in[19];
    const float* ngru_whh = (const float*)d_in[20];
    const float* ngru_bih = (const float*)d_in[21];
    const float* ngru_bhh = (const float*)d_in[22];
    const float* egru_wih = (const float*)d_in[23];
    const float* egru_whh = (const float*)d_in[24];
    const float* egru_bih = (const float*)d_in[25];
    const float* egru_bhh = (const float*)d_in[26];
    const float* op_w = (const float*)d_in[27];
    const float* op_b = (const float*)d_in[28];
    const float* pp_w = (const float*)d_in[29];
    const float* pp_b = (const float*)d_in[30];

    float* out = (float*)d_out;
    float* ws = (float*)d_ws;

    // workspace layout
    float* tmp_e = ws;                                  // 32768*512 (enc hidden / em)
    float* h_edgeA = tmp_e + (size_t)N_RELS * DIM;
    float* tmp_o = h_edgeA + (size_t)N_RELS * DIM;      // 2048*512 (enc hidden / nm)
    float* h_objA = tmp_o + (size_t)N_OBJS * DIM;
    float* gates = h_objA + (size_t)N_OBJS * DIM;       // 4*N_RELS
    float* cnts = gates + 4 * (size_t)N_RELS;           // 2*N_OBJS
    float* cnt_s = cnts;
    float* cnt_o = cnts + N_OBJS;
    float* em = tmp_e;
    float* nm = tmp_o;

    // split-weight area (u16)
    u16* wp = (u16*)(cnts + 2 * N_OBJS);
    const int s_big = DIM * D_IN, s_sq = DIM * DIM, s_gru = 3 * DIM * DIM;
    const int s_op = N_OBJ_CLS * DIM, s_pp = N_REL_CLS * DIM;
    u16 *oe1h = wp; wp += s_big; u16 *oe1l = wp; wp += s_big;
    u16 *pe1h = wp; wp += s_big; u16 *pe1l = wp; wp += s_big;
    u16 *oe2h = wp; wp += s_sq;  u16 *oe2l = wp; wp += s_sq;
    u16 *pe2h = wp; wp += s_sq;  u16 *pe2l = wp; wp += s_sq;
    u16 *nih_h = wp; wp += s_gru; u16 *nih_l = wp; wp += s_gru;
    u16 *nhh_h = wp; wp += s_gru; u16 *nhh_l = wp; wp += s_gru;
    u16 *eih_h = wp; wp += s_gru; u16 *eih_l = wp; wp += s_gru;
    u16 *ehh_h = wp; wp += s_gru; u16 *ehh_l = wp; wp += s_gru;
    u16 *oph = wp; wp += s_op;   u16 *opl = wp; wp += s_op;
    u16 *pph = wp; wp += s_pp;   u16 *ppl = wp; wp += s_pp;

    // GRU chunk buffers (dynamic R based on ws_size): splits (4 x R*512 u16)
    // + gi/gh (2 x R*1536 f32)  => 16384 bytes per row
    const size_t used = (size_t)((char*)wp - (char*)ws);
    int R = 2048;
    if (used + (size_t)8192 * 16384 <= ws_size) R = 8192;
    else if (used + (size_t)4096 * 16384 <= ws_size) R = 4096;
    u16* cxh = wp;
    u16* cxl = cxh + (size_t)R * DIM;
    u16* chh = cxl + (size_t)R * DIM;
    u16* chl = chh + (size_t)R * DIM;
    float* gi = (float*)(chl + (size_t)R * DIM);
    float* gh = gi + (size_t)R * 1536;

    auto cvt = [&](const float* s, u16* h, u16* l, int n) {
        convert_split<<<(n / 4 + 255) / 256, 256, 0, stream>>>(s, h, l, n / 4);
    };
    cvt(oe_w1, oe1h, oe1l, s_big);
    cvt(pe_w1, pe1h, pe1l, s_big);
    cvt(oe_w2, oe2h, oe2l, s_sq);
    cvt(pe_w2, pe2h, pe2l, s_sq);
    cvt(ngru_wih, nih_h, nih_l, s_gru);
    cvt(ngru_whh, nhh_h, nhh_l, s_gru);
    cvt(egru_wih, eih_h, eih_l, s_gru);
    cvt(egru_whh, ehh_h, ehh_l, s_gru);
    cvt(op_w, oph, opl, s_op);
    cvt(pp_w, pph, ppl, s_pp);

    // degree counts
    hipMemsetAsync(cnts, 0, 2 * N_OBJS * sizeof(float), stream);
    count_kernel<<<N_RELS / 256, 256, 0, stream>>>(rel, cnt_s, cnt_o);

    // encoders
    gemm_split<true><<<dim3(DIM / 128, N_OBJS / 128), 256, 0, stream>>>(
        x_obj, oe1h, oe1l, oe_b1, tmp_o, N_OBJS, DIM, D_IN);
    gemm_split<false><<<dim3(DIM / 128, N_OBJS / 128), 256, 0, stream>>>(
        tmp_o, oe2h, oe2l, oe_b2, h_objA, N_OBJS, DIM, DIM);
    gemm_split<true><<<dim3(DIM / 128, N_RELS / 128), 256, 0, stream>>>(
        x_pred, pe1h, pe1l, pe_b1, tmp_e, N_RELS, DIM, D_IN);
    gemm_split<false><<<dim3(DIM / 128, N_RELS / 128), 256, 0, stream>>>(
        tmp_e, pe2h, pe2l, pe_b2, h_edgeA, N_RELS, DIM, DIM);

    // chunked two-pass GRU: gi = X@Wih^T+bih, gh = H@Whh^T+bhh, then combine
    auto run_gru = [&](const float* X, const float* Hin,
                       const u16* WiH, const u16* WiL, const u16* WhH, const u16* WhL,
                       const float* bih, const float* bhh, float* Hout, int Mtot) {
        for (int r0 = 0; r0 < Mtot; r0 += R) {
            const int Rc = (Mtot - r0 < R) ? (Mtot - r0) : R;
            cvt(X + (size_t)r0 * DIM, cxh, cxl, Rc * DIM);
            cvt(Hin + (size_t)r0 * DIM, chh, chl, Rc * DIM);
            gemm_presplit<<<dim3(1536 / 128, Rc / 128), 256, 0, stream>>>(
                cxh, cxl, WiH, WiL, bih, gi, Rc, 1536, DIM);
            gemm_presplit<<<dim3(1536 / 128, Rc / 128), 256, 0, stream>>>(
                chh, chl, WhH, WhL, bhh, gh, Rc, 1536, DIM);
            gru_combine<<<(Rc * 128 + 255) / 256, 256, 0, stream>>>(
                gi, gh, Hin + (size_t)r0 * DIM, Hout + (size_t)r0 * DIM, Rc);
        }
    };

    // message-passing steps; ping-pong via d_out regions, final lands in *_A
    for (int step = 0; step < 2; step++) {
        const float* co = (step == 0) ? h_objA : (out + OFF_HOBJ);
        const float* ce = (step == 0) ? h_edgeA : (out + OFF_HEDGE);
        float* no = (step == 0) ? (out + OFF_HOBJ) : h_objA;
        float* ne = (step == 0) ? (out + OFF_HEDGE) : h_edgeA;

        gates_kernel<<<N_RELS / 4, 256, 0, stream>>>(
            co, ce, rel, g_sn_w, g_sn_b, g_on_w, g_on_b,
            g_se_w, g_se_b, g_oe_w, g_oe_b, gates);

        hipMemsetAsync(nm, 0, (size_t)N_OBJS * DIM * sizeof(float), stream);
        edge_pass<<<N_RELS, 256, 0, stream>>>(co, ce, rel, gates, cnt_s, cnt_o, nm, em);

        run_gru(nm, co, nih_h, nih_l, nhh_h, nhh_l, ngru_bih, ngru_bhh, no, N_OBJS);
        run_gru(em, ce, eih_h, eih_l, ehh_h, ehh_l, egru_bih, egru_bhh, ne, N_RELS);
    }

    // final h_obj/h_edge -> d_out
    hipMemcpyAsync(out + OFF_HOBJ, h_objA, (size_t)N_OBJS * DIM * sizeof(float),
                   hipMemcpyDeviceToDevice, stream);
    hipMemcpyAsync(out + OFF_HEDGE, h_edgeA, (size_t)N_RELS * DIM * sizeof(float),
                   hipMemcpyDeviceToDevice, stream);

    // classifiers
    gemm_split<false><<<dim3((N_OBJ_CLS + 127) / 128, N_OBJS / 128), 256, 0, stream>>>(
        h_objA, oph, opl, op_b, out + OFF_OLOG, N_OBJS, N_OBJ_CLS, DIM);
    gemm_split<false><<<dim3((N_REL_CLS + 127) / 128, N_RELS / 128), 256, 0, stream>>>(
        h_edgeA, pph, ppl, pp_b, out + OFF_PLOG, N_RELS, N_REL_CLS, DIM);

    // labels + rel_inds passthrough
    argmax_kernel<<<N_OBJS / 4, 256, 0, stream>>>(out + OFF_OLOG, out + OFF_LBL);
    relinds_kernel<<<(2 * N_RELS) / 256, 256, 0, stream>>>(rel, out + OFF_RI);
}